// Round 5
// baseline (176.453 us; speedup 1.0000x reference)
//
#include <hip/hip_runtime.h>
#include <hip/hip_bf16.h>
#include <cstdint>
#include <cstddef>

#define SEQ    2048
#define BATCH  2
#define HID    768
#define NH     12
#define HD     64
#define QKV_N  2304

typedef __attribute__((ext_vector_type(8))) short bf16x8;
typedef __attribute__((ext_vector_type(4))) float f32x4;

static __device__ __forceinline__ short f2bf(float x) {
  __hip_bfloat16 h = __float2bfloat16(x);  // RNE
  short s;
  __builtin_memcpy(&s, &h, 2);
  return s;
}
static __device__ __forceinline__ float bf2f(short s) {
  __hip_bfloat16 h;
  __builtin_memcpy(&h, &s, 2);
  return __bfloat162float(h);
}

// ---------------------------------------------------------------------------
// Fused f32 -> bf16 conversion for the three inputs (one launch).
// Block ranges: [0,1536) x, [1536,2400) w_qkv, [2400,2688) w_out.
// ---------------------------------------------------------------------------
__global__ __launch_bounds__(256)
void cvt3_f32_bf16(const float* __restrict__ s0, short* __restrict__ d0,
                   const float* __restrict__ s1, short* __restrict__ d1,
                   const float* __restrict__ s2, short* __restrict__ d2) {
  int bid = blockIdx.x;
  const float* src;
  short* dst;
  if (bid < 1536)      { src = s0; dst = d0; }
  else if (bid < 2400) { src = s1; dst = d1; bid -= 1536; }
  else                 { src = s2; dst = d2; bid -= 2400; }
  const int i = (bid * 256 + threadIdx.x) * 8;
  const float4 a = *reinterpret_cast<const float4*>(src + i);
  const float4 b = *reinterpret_cast<const float4*>(src + i + 4);
  bf16x8 o;
  o[0] = f2bf(a.x); o[1] = f2bf(a.y); o[2] = f2bf(a.z); o[3] = f2bf(a.w);
  o[4] = f2bf(b.x); o[5] = f2bf(b.y); o[6] = f2bf(b.z); o[7] = f2bf(b.w);
  *reinterpret_cast<bf16x8*>(dst + i) = o;
}

// ---------------------------------------------------------------------------
// bf16 MFMA GEMM NT (m97 structure, known-good).
// ---------------------------------------------------------------------------
template <bool BF16_OUT>
__global__ __launch_bounds__(256)
void gemm_nt_mfma(const short* __restrict__ A, const short* __restrict__ B,
                  const float* __restrict__ bias,
                  float* __restrict__ Cf, short* __restrict__ Cb,
                  int M, int N, int K) {
  __shared__ short As[128][64];   // 16 KB
  __shared__ short Bs[128][64];   // 16 KB

  const int t = threadIdx.x;
  const int w = t >> 6;
  const int l = t & 63;
  const int g = l >> 4;
  const int n = l & 15;

  const int m0 = blockIdx.y * 128;
  const int n0 = blockIdx.x * 128;
  const int wr = (w >> 1) * 64;
  const int wc = (w & 1) * 64;

  const int srow = w * 32 + (l >> 3);
  const int scol = (l & 7) * 8;
  const short* Ag = A + (size_t)(m0 + srow) * K + scol;
  const short* Bg = B + (size_t)(n0 + srow) * K + scol;

  f32x4 acc[4][4] = {};

  for (int k0 = 0; k0 < K; k0 += 64) {
    __syncthreads();
#pragma unroll
    for (int it = 0; it < 4; ++it) {
      __builtin_amdgcn_global_load_lds(
          (const __attribute__((address_space(1))) void*)(Ag + (size_t)(it * 8) * K + k0),
          (__attribute__((address_space(3))) void*)(&As[w * 32 + it * 8][0]),
          16, 0, 0);
    }
#pragma unroll
    for (int it = 0; it < 4; ++it) {
      __builtin_amdgcn_global_load_lds(
          (const __attribute__((address_space(1))) void*)(Bg + (size_t)(it * 8) * K + k0),
          (__attribute__((address_space(3))) void*)(&Bs[w * 32 + it * 8][0]),
          16, 0, 0);
    }
    __syncthreads();

#pragma unroll
    for (int kk = 0; kk < 2; ++kk) {
      bf16x8 af[4], bfr[4];
#pragma unroll
      for (int m = 0; m < 4; ++m)
        af[m] = *reinterpret_cast<const bf16x8*>(&As[wr + m * 16 + n][kk * 32 + g * 8]);
#pragma unroll
      for (int j = 0; j < 4; ++j)
        bfr[j] = *reinterpret_cast<const bf16x8*>(&Bs[wc + j * 16 + n][kk * 32 + g * 8]);
#pragma unroll
      for (int m = 0; m < 4; ++m)
#pragma unroll
        for (int j = 0; j < 4; ++j)
          acc[m][j] = __builtin_amdgcn_mfma_f32_16x16x32_bf16(af[m], bfr[j], acc[m][j], 0, 0, 0);
    }
  }

#pragma unroll
  for (int m = 0; m < 4; ++m) {
#pragma unroll
    for (int r = 0; r < 4; ++r) {
      const size_t row = m0 + wr + m * 16 + g * 4 + r;
#pragma unroll
      for (int j = 0; j < 4; ++j) {
        const int col = n0 + wc + j * 16 + n;
        float v = acc[m][j][r];
        if (bias) v += bias[col];
        if (BF16_OUT) Cb[row * N + col] = f2bf(v);
        else          Cf[row * N + col] = v;
      }
    }
  }
}

// ---------------------------------------------------------------------------
// Flash attention, bf16 MFMA, swapped operands; NO K staging (K fragments
// read directly from global — K tile is L1/L2-resident); V double-buffered
// in LDS (single barrier/tile, loads issued early); defer-max (THR=8).
// ---------------------------------------------------------------------------
__global__ __launch_bounds__(256)
void attn_mfma(const short* __restrict__ qkv, short* __restrict__ att) {
  const int bh = blockIdx.x;           // 0..23
  const int qt = blockIdx.y;           // 0..31
  const int b  = bh / NH;
  const int h  = bh % NH;
  const int q0 = qt * 64;

  const int t = threadIdx.x;
  const int w = t >> 6;                // wave 0..3
  const int l = t & 63;
  const int g = l >> 4;                // k-slot group 0..3
  const int n = l & 15;                // q column owned by this lane

  __shared__ short Vt[2][64][72];      // V^T, double-buffered, swizzled
  __shared__ short Ps[4][16][72];      // per-wave P[q][y]

  const short* baseq = qkv + (size_t)b * SEQ * QKV_N + h * HD;
  const short* Kg    = baseq + HID;
  const short* Vg    = baseq + 2 * HID;

  // ---- Q B-fragments (col = q = n), pre-scaled by 0.125 (exact) ----
  bf16x8 qf[2];
  {
    const short* qrow = baseq + (size_t)(q0 + w * 16 + n) * QKV_N;
#pragma unroll
    for (int c = 0; c < 2; ++c) {
      bf16x8 raw = *reinterpret_cast<const bf16x8*>(qrow + c * 32 + g * 8);
#pragma unroll
      for (int j = 0; j < 8; ++j) qf[c][j] = f2bf(bf2f(raw[j]) * 0.125f);
    }
  }

  f32x4 o[4] = {{0.f,0.f,0.f,0.f},{0.f,0.f,0.f,0.f},
                {0.f,0.f,0.f,0.f},{0.f,0.f,0.f,0.f}};
  float mrow = -3e38f;
  float lrow = 0.f;

  const int sr  = t >> 2;              // staging row 0..63 (block-wide)
  const int sdb = t & 3;               // staging 16-wide d block
  const int vys = sr ^ (sdb << 4);     // swizzled y for Vt writes (2-way free)

  // ---- prologue: stage V tile 0 into buffer 0 ----
  {
    const short* vr = Vg + (size_t)sr * QKV_N + sdb * 16;
    bf16x8 v0 = *reinterpret_cast<const bf16x8*>(vr);
    bf16x8 v1 = *reinterpret_cast<const bf16x8*>(vr + 8);
#pragma unroll
    for (int j = 0; j < 8; ++j) Vt[0][sdb * 16 + j][vys] = v0[j];
#pragma unroll
    for (int j = 0; j < 8; ++j) Vt[0][sdb * 16 + 8 + j][vys] = v1[j];
  }
  __syncthreads();

  for (int ti = 0; ti < SEQ / 64; ++ti) {
    const int y0  = ti * 64;
    const int cur = ti & 1;

    // ---- issue next tile's V loads early (latency hides under QK^T) ----
    bf16x8 nv0, nv1;
    const bool have_next = (ti + 1) < SEQ / 64;
    if (have_next) {
      const short* vr = Vg + (size_t)(y0 + 64 + sr) * QKV_N + sdb * 16;
      nv0 = *reinterpret_cast<const bf16x8*>(vr);
      nv1 = *reinterpret_cast<const bf16x8*>(vr + 8);
    }

    // ---- QK^T swapped, K fragments direct from global (L1/L2-hit) ----
    f32x4 sc[4] = {{0.f,0.f,0.f,0.f},{0.f,0.f,0.f,0.f},
                   {0.f,0.f,0.f,0.f},{0.f,0.f,0.f,0.f}};
#pragma unroll
    for (int c = 0; c < 2; ++c) {
#pragma unroll
      for (int kt = 0; kt < 4; ++kt) {
        bf16x8 kb = *reinterpret_cast<const bf16x8*>(
            Kg + (size_t)(y0 + kt * 16 + n) * QKV_N + c * 32 + g * 8);
        sc[kt] = __builtin_amdgcn_mfma_f32_16x16x32_bf16(kb, qf[c], sc[kt], 0, 0, 0);
      }
    }

    // ---- online softmax, defer-max (THR = 8) ----
    {
      float pm = fmaxf(fmaxf(sc[0][0], sc[0][1]), fmaxf(sc[0][2], sc[0][3]));
#pragma unroll
      for (int kt = 1; kt < 4; ++kt)
        pm = fmaxf(pm, fmaxf(fmaxf(sc[kt][0], sc[kt][1]),
                             fmaxf(sc[kt][2], sc[kt][3])));
      pm = fmaxf(pm, __shfl_xor(pm, 16));
      pm = fmaxf(pm, __shfl_xor(pm, 32));
      if (__any(pm - mrow > 8.f)) {       // wave-uniform branch
        const float mnew = fmaxf(mrow, pm);
        const float corr = __expf(mrow - mnew);
        mrow = mnew;
        lrow *= corr;
#pragma unroll
        for (int dt = 0; dt < 4; ++dt)
#pragma unroll
          for (int r = 0; r < 4; ++r) o[dt][r] *= corr;
      }
      float psum = 0.f;
#pragma unroll
      for (int kt = 0; kt < 4; ++kt) {
        short4 pk;
        float p0 = __expf(sc[kt][0] - mrow);
        float p1 = __expf(sc[kt][1] - mrow);
        float p2 = __expf(sc[kt][2] - mrow);
        float p3 = __expf(sc[kt][3] - mrow);
        psum += (p0 + p1) + (p2 + p3);
        pk.x = f2bf(p0); pk.y = f2bf(p1); pk.z = f2bf(p2); pk.w = f2bf(p3);
        *reinterpret_cast<short4*>(&Ps[w][n][kt * 16 + g * 4]) = pk;
      }
      lrow += psum;
    }
    // Ps is wave-local: ds_write -> ds_read ordering via lgkmcnt.

    // ---- PV swapped: o[dt][r] = O[q=n][d = dt*16 + g*4 + r] ----
#pragma unroll
    for (int c = 0; c < 2; ++c) {
      bf16x8 pb = *reinterpret_cast<const bf16x8*>(&Ps[w][n][c * 32 + g * 8]);
#pragma unroll
      for (int dt = 0; dt < 4; ++dt) {
        bf16x8 va = *reinterpret_cast<const bf16x8*>(
            &Vt[cur][dt * 16 + n][(c * 32 + g * 8) ^ (dt << 4)]);
        o[dt] = __builtin_amdgcn_mfma_f32_16x16x32_bf16(va, pb, o[dt], 0, 0, 0);
      }
    }

    // ---- write next V into the other buffer (safe: all waves finished
    //      reading it before the barrier that ended tile ti-1) ----
    if (have_next) {
#pragma unroll
      for (int j = 0; j < 8; ++j) Vt[cur ^ 1][sdb * 16 + j][vys] = nv0[j];
#pragma unroll
      for (int j = 0; j < 8; ++j) Vt[cur ^ 1][sdb * 16 + 8 + j][vys] = nv1[j];
    }
    __syncthreads();   // single barrier per tile
  }

  // ---- epilogue: reduce l across g-lanes, normalize, 4x short4 store ----
  {
    float lt = lrow;
    lt += __shfl_xor(lt, 16);
    lt += __shfl_xor(lt, 32);
    const float linv = 1.f / lt;
    short* orow = att + (size_t)(b * SEQ + q0 + w * 16 + n) * HID + h * HD;
#pragma unroll
    for (int dt = 0; dt < 4; ++dt) {
      short4 ov;
      ov.x = f2bf(o[dt][0] * linv);
      ov.y = f2bf(o[dt][1] * linv);
      ov.z = f2bf(o[dt][2] * linv);
      ov.w = f2bf(o[dt][3] * linv);
      *reinterpret_cast<short4*>(&orow[dt * 16 + g * 4]) = ov;
    }
  }
}

// ---------------------------------------------------------------------------
extern "C" void kernel_launch(void* const* d_in, const int* in_sizes, int n_in,
                              void* d_out, int out_size, void* d_ws, size_t ws_size,
                              hipStream_t stream) {
  const float* x     = (const float*)d_in[0];  // [2,2048,768]
  const float* w_qkv = (const float*)d_in[1];  // [2304,768]
  const float* w_out = (const float*)d_in[2];  // [768,768]
  const float* b_out = (const float*)d_in[3];  // [768]
  float* out = (float*)d_out;                  // [2,2048,768]

  const int NX  = BATCH * SEQ * HID;   // 3,145,728
  const int NWQ = QKV_N * HID;         // 1,769,472
  const int NWO = HID * HID;           //   589,824

  char* ws = (char*)d_ws;
  short* xb   = (short*)ws;  ws += (size_t)NX  * 2;
  short* wqb  = (short*)ws;  ws += (size_t)NWQ * 2;
  short* wob  = (short*)ws;  ws += (size_t)NWO * 2;
  short* qkvb = (short*)ws;  ws += (size_t)BATCH * SEQ * QKV_N * 2;
  short* attb = (short*)ws;  // [4096,768] bf16

  const dim3 blk(256);

  // one fused conversion launch (2688 blocks)
  cvt3_f32_bf16<<<dim3(2688), blk, 0, stream>>>(x, xb, w_qkv, wqb, w_out, wob);

  // QKV projection: [4096,2304] = xb @ wqb^T  (bf16 out)
  gemm_nt_mfma<true><<<dim3(QKV_N / 128, (BATCH * SEQ) / 128), blk, 0, stream>>>(
      xb, wqb, nullptr, nullptr, qkvb, BATCH * SEQ, QKV_N, HID);

  // bf16 MFMA flash attention -> attb (bf16)
  attn_mfma<<<dim3(BATCH * NH, SEQ / 64), blk, 0, stream>>>(qkvb, attb);

  // out projection: out = attb @ wob^T + b_out  (f32 out)
  gemm_nt_mfma<false><<<dim3(HID / 128, (BATCH * SEQ) / 128), blk, 0, stream>>>(
      attb, wob, b_out, out, nullptr, BATCH * SEQ, HID, HID);
}

// Round 6
// 137.136 us; speedup vs baseline: 1.2867x; 1.2867x over previous
//
#include <hip/hip_runtime.h>
#include <hip/hip_bf16.h>
#include <cstdint>
#include <cstddef>

#define SEQ    2048
#define BATCH  2
#define HID    768
#define NH     12
#define HD     64
#define QKV_N  2304

typedef __attribute__((ext_vector_type(8))) short bf16x8;
typedef __attribute__((ext_vector_type(4))) float f32x4;

static __device__ __forceinline__ short f2bf(float x) {
  __hip_bfloat16 h = __float2bfloat16(x);  // RNE
  short s;
  __builtin_memcpy(&s, &h, 2);
  return s;
}
static __device__ __forceinline__ float bf2f(short s) {
  __hip_bfloat16 h;
  __builtin_memcpy(&h, &s, 2);
  return __bfloat162float(h);
}

// ---------------------------------------------------------------------------
// Fused f32 -> bf16 conversion for the three inputs (one launch).
// ---------------------------------------------------------------------------
__global__ __launch_bounds__(256)
void cvt3_f32_bf16(const float* __restrict__ s0, short* __restrict__ d0,
                   const float* __restrict__ s1, short* __restrict__ d1,
                   const float* __restrict__ s2, short* __restrict__ d2) {
  int bid = blockIdx.x;
  const float* src;
  short* dst;
  if (bid < 1536)      { src = s0; dst = d0; }
  else if (bid < 2400) { src = s1; dst = d1; bid -= 1536; }
  else                 { src = s2; dst = d2; bid -= 2400; }
  const int i = (bid * 256 + threadIdx.x) * 8;
  const float4 a = *reinterpret_cast<const float4*>(src + i);
  const float4 b = *reinterpret_cast<const float4*>(src + i + 4);
  bf16x8 o;
  o[0] = f2bf(a.x); o[1] = f2bf(a.y); o[2] = f2bf(a.z); o[3] = f2bf(a.w);
  o[4] = f2bf(b.x); o[5] = f2bf(b.y); o[6] = f2bf(b.z); o[7] = f2bf(b.w);
  *reinterpret_cast<bf16x8*>(dst + i) = o;
}

// ---------------------------------------------------------------------------
// bf16 MFMA GEMM NT (m97 structure, known-good).
// ---------------------------------------------------------------------------
template <bool BF16_OUT>
__global__ __launch_bounds__(256)
void gemm_nt_mfma(const short* __restrict__ A, const short* __restrict__ B,
                  const float* __restrict__ bias,
                  float* __restrict__ Cf, short* __restrict__ Cb,
                  int M, int N, int K) {
  __shared__ short As[128][64];   // 16 KB
  __shared__ short Bs[128][64];   // 16 KB

  const int t = threadIdx.x;
  const int w = t >> 6;
  const int l = t & 63;
  const int g = l >> 4;
  const int n = l & 15;

  const int m0 = blockIdx.y * 128;
  const int n0 = blockIdx.x * 128;
  const int wr = (w >> 1) * 64;
  const int wc = (w & 1) * 64;

  const int srow = w * 32 + (l >> 3);
  const int scol = (l & 7) * 8;
  const short* Ag = A + (size_t)(m0 + srow) * K + scol;
  const short* Bg = B + (size_t)(n0 + srow) * K + scol;

  f32x4 acc[4][4] = {};

  for (int k0 = 0; k0 < K; k0 += 64) {
    __syncthreads();
#pragma unroll
    for (int it = 0; it < 4; ++it) {
      __builtin_amdgcn_global_load_lds(
          (const __attribute__((address_space(1))) void*)(Ag + (size_t)(it * 8) * K + k0),
          (__attribute__((address_space(3))) void*)(&As[w * 32 + it * 8][0]),
          16, 0, 0);
    }
#pragma unroll
    for (int it = 0; it < 4; ++it) {
      __builtin_amdgcn_global_load_lds(
          (const __attribute__((address_space(1))) void*)(Bg + (size_t)(it * 8) * K + k0),
          (__attribute__((address_space(3))) void*)(&Bs[w * 32 + it * 8][0]),
          16, 0, 0);
    }
    __syncthreads();

#pragma unroll
    for (int kk = 0; kk < 2; ++kk) {
      bf16x8 af[4], bfr[4];
#pragma unroll
      for (int m = 0; m < 4; ++m)
        af[m] = *reinterpret_cast<const bf16x8*>(&As[wr + m * 16 + n][kk * 32 + g * 8]);
#pragma unroll
      for (int j = 0; j < 4; ++j)
        bfr[j] = *reinterpret_cast<const bf16x8*>(&Bs[wc + j * 16 + n][kk * 32 + g * 8]);
#pragma unroll
      for (int m = 0; m < 4; ++m)
#pragma unroll
        for (int j = 0; j < 4; ++j)
          acc[m][j] = __builtin_amdgcn_mfma_f32_16x16x32_bf16(af[m], bfr[j], acc[m][j], 0, 0, 0);
    }
  }

#pragma unroll
  for (int m = 0; m < 4; ++m) {
#pragma unroll
    for (int r = 0; r < 4; ++r) {
      const size_t row = m0 + wr + m * 16 + g * 4 + r;
#pragma unroll
      for (int j = 0; j < 4; ++j) {
        const int col = n0 + wc + j * 16 + n;
        float v = acc[m][j][r];
        if (bias) v += bias[col];
        if (BF16_OUT) Cb[row * N + col] = f2bf(v);
        else          Cf[row * N + col] = v;
      }
    }
  }
}

// ---------------------------------------------------------------------------
// Flash attention, bf16 MFMA, swapped operands. Round-4 data path (K staged
// in LDS) + register prefetch of next K/V tile (T14: issue loads at tile
// top, ds_write after PV), double-buffered K/V LDS, single barrier/tile,
// defer-max (THR=8).
// ---------------------------------------------------------------------------
__global__ __launch_bounds__(256)
void attn_mfma(const short* __restrict__ qkv, short* __restrict__ att) {
  const int bh = blockIdx.x;           // 0..23
  const int qt = blockIdx.y;           // 0..31
  const int b  = bh / NH;
  const int h  = bh % NH;
  const int q0 = qt * 64;

  const int t = threadIdx.x;
  const int w = t >> 6;                // wave 0..3
  const int l = t & 63;
  const int g = l >> 4;                // k-slot group 0..3
  const int n = l & 15;                // q column owned by this lane

  __shared__ short Kx[2][64][72];      // K row-major, double-buffered
  __shared__ short Vt[2][64][72];      // V^T swizzled, double-buffered
  __shared__ short Ps[4][16][72];      // per-wave P[q][y]

  const short* baseq = qkv + (size_t)b * SEQ * QKV_N + h * HD;
  const short* Kg    = baseq + HID;
  const short* Vg    = baseq + 2 * HID;

  // ---- Q B-fragments (col = q = n), pre-scaled by 0.125 (exact) ----
  bf16x8 qf[2];
  {
    const short* qrow = baseq + (size_t)(q0 + w * 16 + n) * QKV_N;
#pragma unroll
    for (int c = 0; c < 2; ++c) {
      bf16x8 raw = *reinterpret_cast<const bf16x8*>(qrow + c * 32 + g * 8);
#pragma unroll
      for (int j = 0; j < 8; ++j) qf[c][j] = f2bf(bf2f(raw[j]) * 0.125f);
    }
  }

  f32x4 o[4] = {{0.f,0.f,0.f,0.f},{0.f,0.f,0.f,0.f},
                {0.f,0.f,0.f,0.f},{0.f,0.f,0.f,0.f}};
  float mrow = -3e38f;
  float lrow = 0.f;

  const int sr  = t >> 2;              // staging row 0..63 (block-wide)
  const int sdb = t & 3;               // staging 16-wide d block
  const int vys = sr ^ (sdb << 4);     // swizzled y for Vt writes

  // ---- prologue: stage K/V tile 0 into buffer 0 ----
  {
    const short* kr = Kg + (size_t)sr * QKV_N + sdb * 16;
    bf16x8 k0 = *reinterpret_cast<const bf16x8*>(kr);
    bf16x8 k1 = *reinterpret_cast<const bf16x8*>(kr + 8);
    *reinterpret_cast<bf16x8*>(&Kx[0][sr][sdb * 16])     = k0;
    *reinterpret_cast<bf16x8*>(&Kx[0][sr][sdb * 16 + 8]) = k1;

    const short* vr = Vg + (size_t)sr * QKV_N + sdb * 16;
    bf16x8 v0 = *reinterpret_cast<const bf16x8*>(vr);
    bf16x8 v1 = *reinterpret_cast<const bf16x8*>(vr + 8);
#pragma unroll
    for (int j = 0; j < 8; ++j) Vt[0][sdb * 16 + j][vys] = v0[j];
#pragma unroll
    for (int j = 0; j < 8; ++j) Vt[0][sdb * 16 + 8 + j][vys] = v1[j];
  }
  __syncthreads();

  for (int ti = 0; ti < SEQ / 64; ++ti) {
    const int y0  = ti * 64;
    const int cur = ti & 1;

    // ---- issue next tile's K/V loads into registers (consumed after PV;
    //      global latency hides under this tile's MFMA + softmax) ----
    bf16x8 nk0, nk1, nv0, nv1;
    const bool have_next = (ti + 1) < SEQ / 64;
    if (have_next) {
      const short* kr = Kg + (size_t)(y0 + 64 + sr) * QKV_N + sdb * 16;
      nk0 = *reinterpret_cast<const bf16x8*>(kr);
      nk1 = *reinterpret_cast<const bf16x8*>(kr + 8);
      const short* vr = Vg + (size_t)(y0 + 64 + sr) * QKV_N + sdb * 16;
      nv0 = *reinterpret_cast<const bf16x8*>(vr);
      nv1 = *reinterpret_cast<const bf16x8*>(vr + 8);
    }

    // ---- QK^T swapped: lane holds S[kv = kt*16+g*4+r][q = n] ----
    f32x4 sc[4] = {{0.f,0.f,0.f,0.f},{0.f,0.f,0.f,0.f},
                   {0.f,0.f,0.f,0.f},{0.f,0.f,0.f,0.f}};
#pragma unroll
    for (int c = 0; c < 2; ++c) {
#pragma unroll
      for (int kt = 0; kt < 4; ++kt) {
        bf16x8 kb = *reinterpret_cast<const bf16x8*>(&Kx[cur][kt * 16 + n][c * 32 + g * 8]);
        sc[kt] = __builtin_amdgcn_mfma_f32_16x16x32_bf16(kb, qf[c], sc[kt], 0, 0, 0);
      }
    }

    // ---- online softmax, defer-max (THR = 8) ----
    {
      float pm = fmaxf(fmaxf(sc[0][0], sc[0][1]), fmaxf(sc[0][2], sc[0][3]));
#pragma unroll
      for (int kt = 1; kt < 4; ++kt)
        pm = fmaxf(pm, fmaxf(fmaxf(sc[kt][0], sc[kt][1]),
                             fmaxf(sc[kt][2], sc[kt][3])));
      pm = fmaxf(pm, __shfl_xor(pm, 16));
      pm = fmaxf(pm, __shfl_xor(pm, 32));
      if (__any(pm - mrow > 8.f)) {       // wave-uniform branch
        const float mnew = fmaxf(mrow, pm);
        const float corr = __expf(mrow - mnew);
        mrow = mnew;
        lrow *= corr;
#pragma unroll
        for (int dt = 0; dt < 4; ++dt)
#pragma unroll
          for (int r = 0; r < 4; ++r) o[dt][r] *= corr;
      }
      float psum = 0.f;
#pragma unroll
      for (int kt = 0; kt < 4; ++kt) {
        short4 pk;
        float p0 = __expf(sc[kt][0] - mrow);
        float p1 = __expf(sc[kt][1] - mrow);
        float p2 = __expf(sc[kt][2] - mrow);
        float p3 = __expf(sc[kt][3] - mrow);
        psum += (p0 + p1) + (p2 + p3);
        pk.x = f2bf(p0); pk.y = f2bf(p1); pk.z = f2bf(p2); pk.w = f2bf(p3);
        *reinterpret_cast<short4*>(&Ps[w][n][kt * 16 + g * 4]) = pk;
      }
      lrow += psum;
    }
    // Ps is wave-local: ds_write -> ds_read ordering via lgkmcnt.

    // ---- PV swapped: o[dt][r] = O[q=n][d = dt*16 + g*4 + r] ----
#pragma unroll
    for (int c = 0; c < 2; ++c) {
      bf16x8 pb = *reinterpret_cast<const bf16x8*>(&Ps[w][n][c * 32 + g * 8]);
#pragma unroll
      for (int dt = 0; dt < 4; ++dt) {
        bf16x8 va = *reinterpret_cast<const bf16x8*>(
            &Vt[cur][dt * 16 + n][(c * 32 + g * 8) ^ (dt << 4)]);
        o[dt] = __builtin_amdgcn_mfma_f32_16x16x32_bf16(va, pb, o[dt], 0, 0, 0);
      }
    }

    // ---- write prefetched K/V into the other buffer (safe: all waves
    //      finished reading it before the end-of-previous-tile barrier) ----
    if (have_next) {
      const int nxt = cur ^ 1;
      *reinterpret_cast<bf16x8*>(&Kx[nxt][sr][sdb * 16])     = nk0;
      *reinterpret_cast<bf16x8*>(&Kx[nxt][sr][sdb * 16 + 8]) = nk1;
#pragma unroll
      for (int j = 0; j < 8; ++j) Vt[nxt][sdb * 16 + j][vys] = nv0[j];
#pragma unroll
      for (int j = 0; j < 8; ++j) Vt[nxt][sdb * 16 + 8 + j][vys] = nv1[j];
    }
    __syncthreads();   // single barrier per tile
  }

  // ---- epilogue: reduce l across g-lanes, normalize, 4x short4 store ----
  {
    float lt = lrow;
    lt += __shfl_xor(lt, 16);
    lt += __shfl_xor(lt, 32);
    const float linv = 1.f / lt;
    short* orow = att + (size_t)(b * SEQ + q0 + w * 16 + n) * HID + h * HD;
#pragma unroll
    for (int dt = 0; dt < 4; ++dt) {
      short4 ov;
      ov.x = f2bf(o[dt][0] * linv);
      ov.y = f2bf(o[dt][1] * linv);
      ov.z = f2bf(o[dt][2] * linv);
      ov.w = f2bf(o[dt][3] * linv);
      *reinterpret_cast<short4*>(&orow[dt * 16 + g * 4]) = ov;
    }
  }
}

// ---------------------------------------------------------------------------
extern "C" void kernel_launch(void* const* d_in, const int* in_sizes, int n_in,
                              void* d_out, int out_size, void* d_ws, size_t ws_size,
                              hipStream_t stream) {
  const float* x     = (const float*)d_in[0];  // [2,2048,768]
  const float* w_qkv = (const float*)d_in[1];  // [2304,768]
  const float* w_out = (const float*)d_in[2];  // [768,768]
  const float* b_out = (const float*)d_in[3];  // [768]
  float* out = (float*)d_out;                  // [2,2048,768]

  const int NX  = BATCH * SEQ * HID;   // 3,145,728
  const int NWQ = QKV_N * HID;         // 1,769,472
  const int NWO = HID * HID;           //   589,824

  char* ws = (char*)d_ws;
  short* xb   = (short*)ws;  ws += (size_t)NX  * 2;
  short* wqb  = (short*)ws;  ws += (size_t)NWQ * 2;
  short* wob  = (short*)ws;  ws += (size_t)NWO * 2;
  short* qkvb = (short*)ws;  ws += (size_t)BATCH * SEQ * QKV_N * 2;
  short* attb = (short*)ws;  // [4096,768] bf16

  const dim3 blk(256);

  cvt3_f32_bf16<<<dim3(2688), blk, 0, stream>>>(x, xb, w_qkv, wqb, w_out, wob);

  // QKV projection: [4096,2304] = xb @ wqb^T  (bf16 out)
  gemm_nt_mfma<true><<<dim3(QKV_N / 128, (BATCH * SEQ) / 128), blk, 0, stream>>>(
      xb, wqb, nullptr, nullptr, qkvb, BATCH * SEQ, QKV_N, HID);

  // bf16 MFMA flash attention -> attb (bf16)
  attn_mfma<<<dim3(BATCH * NH, SEQ / 64), blk, 0, stream>>>(qkvb, attb);

  // out projection: out = attb @ wob^T + b_out  (f32 out)
  gemm_nt_mfma<false><<<dim3(HID / 128, (BATCH * SEQ) / 128), blk, 0, stream>>>(
      attb, wob, b_out, out, nullptr, BATCH * SEQ, HID, HID);
}

// Round 7
// 135.916 us; speedup vs baseline: 1.2982x; 1.0090x over previous
//
#include <hip/hip_runtime.h>
#include <hip/hip_bf16.h>
#include <cstdint>
#include <cstddef>

#define SEQ    2048
#define BATCH  2
#define HID    768
#define NH     12
#define HD     64
#define QKV_N  2304
#define NT     (SEQ / 64)

typedef __attribute__((ext_vector_type(8))) short bf16x8;
typedef __attribute__((ext_vector_type(4))) float f32x4;

static __device__ __forceinline__ short f2bf(float x) {
  __hip_bfloat16 h = __float2bfloat16(x);  // RNE
  short s;
  __builtin_memcpy(&s, &h, 2);
  return s;
}
static __device__ __forceinline__ float bf2f(short s) {
  __hip_bfloat16 h;
  __builtin_memcpy(&h, &s, 2);
  return __bfloat162float(h);
}

// ---------------------------------------------------------------------------
// Fused f32 -> bf16 conversion for the three inputs (one launch).
// ---------------------------------------------------------------------------
__global__ __launch_bounds__(256)
void cvt3_f32_bf16(const float* __restrict__ s0, short* __restrict__ d0,
                   const float* __restrict__ s1, short* __restrict__ d1,
                   const float* __restrict__ s2, short* __restrict__ d2) {
  int bid = blockIdx.x;
  const float* src;
  short* dst;
  if (bid < 1536)      { src = s0; dst = d0; }
  else if (bid < 2400) { src = s1; dst = d1; bid -= 1536; }
  else                 { src = s2; dst = d2; bid -= 2400; }
  const int i = (bid * 256 + threadIdx.x) * 8;
  const float4 a = *reinterpret_cast<const float4*>(src + i);
  const float4 b = *reinterpret_cast<const float4*>(src + i + 4);
  bf16x8 o;
  o[0] = f2bf(a.x); o[1] = f2bf(a.y); o[2] = f2bf(a.z); o[3] = f2bf(a.w);
  o[4] = f2bf(b.x); o[5] = f2bf(b.y); o[6] = f2bf(b.z); o[7] = f2bf(b.w);
  *reinterpret_cast<bf16x8*>(dst + i) = o;
}

// ---------------------------------------------------------------------------
// bf16 MFMA GEMM NT (m97 structure, known-good).
// ---------------------------------------------------------------------------
template <bool BF16_OUT>
__global__ __launch_bounds__(256)
void gemm_nt_mfma(const short* __restrict__ A, const short* __restrict__ B,
                  const float* __restrict__ bias,
                  float* __restrict__ Cf, short* __restrict__ Cb,
                  int M, int N, int K) {
  __shared__ short As[128][64];   // 16 KB
  __shared__ short Bs[128][64];   // 16 KB

  const int t = threadIdx.x;
  const int w = t >> 6;
  const int l = t & 63;
  const int g = l >> 4;
  const int n = l & 15;

  const int m0 = blockIdx.y * 128;
  const int n0 = blockIdx.x * 128;
  const int wr = (w >> 1) * 64;
  const int wc = (w & 1) * 64;

  const int srow = w * 32 + (l >> 3);
  const int scol = (l & 7) * 8;
  const short* Ag = A + (size_t)(m0 + srow) * K + scol;
  const short* Bg = B + (size_t)(n0 + srow) * K + scol;

  f32x4 acc[4][4] = {};

  for (int k0 = 0; k0 < K; k0 += 64) {
    __syncthreads();
#pragma unroll
    for (int it = 0; it < 4; ++it) {
      __builtin_amdgcn_global_load_lds(
          (const __attribute__((address_space(1))) void*)(Ag + (size_t)(it * 8) * K + k0),
          (__attribute__((address_space(3))) void*)(&As[w * 32 + it * 8][0]),
          16, 0, 0);
    }
#pragma unroll
    for (int it = 0; it < 4; ++it) {
      __builtin_amdgcn_global_load_lds(
          (const __attribute__((address_space(1))) void*)(Bg + (size_t)(it * 8) * K + k0),
          (__attribute__((address_space(3))) void*)(&Bs[w * 32 + it * 8][0]),
          16, 0, 0);
    }
    __syncthreads();

#pragma unroll
    for (int kk = 0; kk < 2; ++kk) {
      bf16x8 af[4], bfr[4];
#pragma unroll
      for (int m = 0; m < 4; ++m)
        af[m] = *reinterpret_cast<const bf16x8*>(&As[wr + m * 16 + n][kk * 32 + g * 8]);
#pragma unroll
      for (int j = 0; j < 4; ++j)
        bfr[j] = *reinterpret_cast<const bf16x8*>(&Bs[wc + j * 16 + n][kk * 32 + g * 8]);
#pragma unroll
      for (int m = 0; m < 4; ++m)
#pragma unroll
        for (int j = 0; j < 4; ++j)
          acc[m][j] = __builtin_amdgcn_mfma_f32_16x16x32_bf16(af[m], bfr[j], acc[m][j], 0, 0, 0);
    }
  }

#pragma unroll
  for (int m = 0; m < 4; ++m) {
#pragma unroll
    for (int r = 0; r < 4; ++r) {
      const size_t row = m0 + wr + m * 16 + g * 4 + r;
#pragma unroll
      for (int j = 0; j < 4; ++j) {
        const int col = n0 + wc + j * 16 + n;
        float v = acc[m][j][r];
        if (bias) v += bias[col];
        if (BF16_OUT) Cb[row * N + col] = f2bf(v);
        else          Cf[row * N + col] = v;
      }
    }
  }
}

// ---------------------------------------------------------------------------
// Flash attention, bf16 MFMA, swapped operands, SOFTWARE-PIPELINED:
// iteration ti computes softmax(ti) || QK^T(ti+1) || PV(ti). QK^T(ti+1) is
// independent of softmax(ti)/PV(ti) -> MFMA pipe stays fed during the
// softmax VALU window (separate pipes, m114). K/V double-buffered; register
// prefetch (K two tiles ahead, V one); one barrier per tile; defer-max.
// Slot rotation at iter ti: Kx read (ti+1)&1 / write ti&1;
//                           Vt read ti&1     / write (ti+1)&1.  (disjoint)
// ---------------------------------------------------------------------------
__global__ __launch_bounds__(256)
void attn_mfma(const short* __restrict__ qkv, short* __restrict__ att) {
  const int bh = blockIdx.x;           // 0..23
  const int qt = blockIdx.y;           // 0..31
  const int b  = bh / NH;
  const int h  = bh % NH;
  const int q0 = qt * 64;

  const int t = threadIdx.x;
  const int w = t >> 6;                // wave 0..3
  const int l = t & 63;
  const int g = l >> 4;                // k-slot group 0..3
  const int n = l & 15;                // q column owned by this lane

  __shared__ short Kx[2][64][72];      // K row-major, double-buffered
  __shared__ short Vt[2][64][72];      // V^T swizzled, double-buffered
  __shared__ short Ps[4][16][72];      // per-wave P[q][y]

  const short* baseq = qkv + (size_t)b * SEQ * QKV_N + h * HD;
  const short* Kg    = baseq + HID;
  const short* Vg    = baseq + 2 * HID;

  // ---- Q B-fragments (col = q = n), pre-scaled by 0.125 (exact) ----
  bf16x8 qf[2];
  {
    const short* qrow = baseq + (size_t)(q0 + w * 16 + n) * QKV_N;
#pragma unroll
    for (int c = 0; c < 2; ++c) {
      bf16x8 raw = *reinterpret_cast<const bf16x8*>(qrow + c * 32 + g * 8);
#pragma unroll
      for (int j = 0; j < 8; ++j) qf[c][j] = f2bf(bf2f(raw[j]) * 0.125f);
    }
  }

  f32x4 o[4] = {{0.f,0.f,0.f,0.f},{0.f,0.f,0.f,0.f},
                {0.f,0.f,0.f,0.f},{0.f,0.f,0.f,0.f}};
  float mrow = -3e38f;
  float lrow = 0.f;

  const int sr  = t >> 2;              // staging row 0..63 (block-wide)
  const int sdb = t & 3;               // staging 16-wide d block
  const int vys = sr ^ (sdb << 4);     // swizzled y for Vt writes

  // ---- prologue: stage K(0)->slot0, K(1)->slot1, V(0)->slot0 ----
  {
    const short* k0p = Kg + (size_t)sr * QKV_N + sdb * 16;
    const short* k1p = Kg + (size_t)(64 + sr) * QKV_N + sdb * 16;
    const short* v0p = Vg + (size_t)sr * QKV_N + sdb * 16;
    bf16x8 ka0 = *reinterpret_cast<const bf16x8*>(k0p);
    bf16x8 ka1 = *reinterpret_cast<const bf16x8*>(k0p + 8);
    bf16x8 kb0 = *reinterpret_cast<const bf16x8*>(k1p);
    bf16x8 kb1 = *reinterpret_cast<const bf16x8*>(k1p + 8);
    bf16x8 va0 = *reinterpret_cast<const bf16x8*>(v0p);
    bf16x8 va1 = *reinterpret_cast<const bf16x8*>(v0p + 8);
    *reinterpret_cast<bf16x8*>(&Kx[0][sr][sdb * 16])     = ka0;
    *reinterpret_cast<bf16x8*>(&Kx[0][sr][sdb * 16 + 8]) = ka1;
    *reinterpret_cast<bf16x8*>(&Kx[1][sr][sdb * 16])     = kb0;
    *reinterpret_cast<bf16x8*>(&Kx[1][sr][sdb * 16 + 8]) = kb1;
#pragma unroll
    for (int j = 0; j < 8; ++j) Vt[0][sdb * 16 + j][vys] = va0[j];
#pragma unroll
    for (int j = 0; j < 8; ++j) Vt[0][sdb * 16 + 8 + j][vys] = va1[j];
  }
  __syncthreads();

  // ---- QK^T(0) ----
  f32x4 sc[4] = {{0.f,0.f,0.f,0.f},{0.f,0.f,0.f,0.f},
                 {0.f,0.f,0.f,0.f},{0.f,0.f,0.f,0.f}};
#pragma unroll
  for (int c = 0; c < 2; ++c)
#pragma unroll
    for (int kt = 0; kt < 4; ++kt) {
      bf16x8 kb = *reinterpret_cast<const bf16x8*>(&Kx[0][kt * 16 + n][c * 32 + g * 8]);
      sc[kt] = __builtin_amdgcn_mfma_f32_16x16x32_bf16(kb, qf[c], sc[kt], 0, 0, 0);
    }

  for (int ti = 0; ti < NT; ++ti) {
    const int cur = ti & 1;
    const bool have_k2 = (ti + 2) < NT;
    const bool have_v1 = (ti + 1) < NT;

    // ---- register prefetch: K(ti+2), V(ti+1) (consumed after PV) ----
    bf16x8 nk0, nk1, nv0, nv1;
    if (have_k2) {
      const short* kr = Kg + (size_t)((ti + 2) * 64 + sr) * QKV_N + sdb * 16;
      nk0 = *reinterpret_cast<const bf16x8*>(kr);
      nk1 = *reinterpret_cast<const bf16x8*>(kr + 8);
    }
    if (have_v1) {
      const short* vr = Vg + (size_t)((ti + 1) * 64 + sr) * QKV_N + sdb * 16;
      nv0 = *reinterpret_cast<const bf16x8*>(vr);
      nv1 = *reinterpret_cast<const bf16x8*>(vr + 8);
    }

    // ---- softmax(ti), defer-max (THR = 8) ----
    {
      float pm = fmaxf(fmaxf(sc[0][0], sc[0][1]), fmaxf(sc[0][2], sc[0][3]));
#pragma unroll
      for (int kt = 1; kt < 4; ++kt)
        pm = fmaxf(pm, fmaxf(fmaxf(sc[kt][0], sc[kt][1]),
                             fmaxf(sc[kt][2], sc[kt][3])));
      pm = fmaxf(pm, __shfl_xor(pm, 16));
      pm = fmaxf(pm, __shfl_xor(pm, 32));
      if (__any(pm - mrow > 8.f)) {       // wave-uniform branch
        const float mnew = fmaxf(mrow, pm);
        const float corr = __expf(mrow - mnew);
        mrow = mnew;
        lrow *= corr;
#pragma unroll
        for (int dt = 0; dt < 4; ++dt)
#pragma unroll
          for (int r = 0; r < 4; ++r) o[dt][r] *= corr;
      }
      float psum = 0.f;
#pragma unroll
      for (int kt = 0; kt < 4; ++kt) {
        short4 pk;
        float p0 = __expf(sc[kt][0] - mrow);
        float p1 = __expf(sc[kt][1] - mrow);
        float p2 = __expf(sc[kt][2] - mrow);
        float p3 = __expf(sc[kt][3] - mrow);
        psum += (p0 + p1) + (p2 + p3);
        pk.x = f2bf(p0); pk.y = f2bf(p1); pk.z = f2bf(p2); pk.w = f2bf(p3);
        *reinterpret_cast<short4*>(&Ps[w][n][kt * 16 + g * 4]) = pk;
      }
      lrow += psum;
    }

    // ---- QK^T(ti+1) — independent of softmax(ti)/PV(ti); keeps the MFMA
    //      pipe busy during the softmax/Ps window (SSA renames sc) ----
    if (have_v1) {
#pragma unroll
      for (int kt = 0; kt < 4; ++kt) sc[kt] = f32x4{0.f, 0.f, 0.f, 0.f};
#pragma unroll
      for (int c = 0; c < 2; ++c)
#pragma unroll
        for (int kt = 0; kt < 4; ++kt) {
          bf16x8 kb = *reinterpret_cast<const bf16x8*>(
              &Kx[cur ^ 1][kt * 16 + n][c * 32 + g * 8]);
          sc[kt] = __builtin_amdgcn_mfma_f32_16x16x32_bf16(kb, qf[c], sc[kt], 0, 0, 0);
        }
    }

    // ---- PV(ti): o[dt][r] = O[q=n][d = dt*16 + g*4 + r] ----
    // Ps is wave-local: ds_write -> ds_read ordering via lgkmcnt.
#pragma unroll
    for (int c = 0; c < 2; ++c) {
      bf16x8 pb = *reinterpret_cast<const bf16x8*>(&Ps[w][n][c * 32 + g * 8]);
#pragma unroll
      for (int dt = 0; dt < 4; ++dt) {
        bf16x8 va = *reinterpret_cast<const bf16x8*>(
            &Vt[cur][dt * 16 + n][(c * 32 + g * 8) ^ (dt << 4)]);
        o[dt] = __builtin_amdgcn_mfma_f32_16x16x32_bf16(va, pb, o[dt], 0, 0, 0);
      }
    }

    // ---- write prefetched K(ti+2)->Kx[ti&1], V(ti+1)->Vt[(ti+1)&1] ----
    if (have_k2) {
      *reinterpret_cast<bf16x8*>(&Kx[cur][sr][sdb * 16])     = nk0;
      *reinterpret_cast<bf16x8*>(&Kx[cur][sr][sdb * 16 + 8]) = nk1;
    }
    if (have_v1) {
#pragma unroll
      for (int j = 0; j < 8; ++j) Vt[cur ^ 1][sdb * 16 + j][vys] = nv0[j];
#pragma unroll
      for (int j = 0; j < 8; ++j) Vt[cur ^ 1][sdb * 16 + 8 + j][vys] = nv1[j];
    }
    __syncthreads();   // single barrier per tile
  }

  // ---- epilogue: reduce l across g-lanes, normalize, 4x short4 store ----
  {
    float lt = lrow;
    lt += __shfl_xor(lt, 16);
    lt += __shfl_xor(lt, 32);
    const float linv = 1.f / lt;
    short* orow = att + (size_t)(b * SEQ + q0 + w * 16 + n) * HID + h * HD;
#pragma unroll
    for (int dt = 0; dt < 4; ++dt) {
      short4 ov;
      ov.x = f2bf(o[dt][0] * linv);
      ov.y = f2bf(o[dt][1] * linv);
      ov.z = f2bf(o[dt][2] * linv);
      ov.w = f2bf(o[dt][3] * linv);
      *reinterpret_cast<short4*>(&orow[dt * 16 + g * 4]) = ov;
    }
  }
}

// ---------------------------------------------------------------------------
extern "C" void kernel_launch(void* const* d_in, const int* in_sizes, int n_in,
                              void* d_out, int out_size, void* d_ws, size_t ws_size,
                              hipStream_t stream) {
  const float* x     = (const float*)d_in[0];  // [2,2048,768]
  const float* w_qkv = (const float*)d_in[1];  // [2304,768]
  const float* w_out = (const float*)d_in[2];  // [768,768]
  const float* b_out = (const float*)d_in[3];  // [768]
  float* out = (float*)d_out;                  // [2,2048,768]

  const int NX  = BATCH * SEQ * HID;   // 3,145,728
  const int NWQ = QKV_N * HID;         // 1,769,472
  const int NWO = HID * HID;           //   589,824

  char* ws = (char*)d_ws;
  short* xb   = (short*)ws;  ws += (size_t)NX  * 2;
  short* wqb  = (short*)ws;  ws += (size_t)NWQ * 2;
  short* wob  = (short*)ws;  ws += (size_t)NWO * 2;
  short* qkvb = (short*)ws;  ws += (size_t)BATCH * SEQ * QKV_N * 2;
  short* attb = (short*)ws;  // [4096,768] bf16

  const dim3 blk(256);

  cvt3_f32_bf16<<<dim3(2688), blk, 0, stream>>>(x, xb, w_qkv, wqb, w_out, wob);

  // QKV projection: [4096,2304] = xb @ wqb^T  (bf16 out)
  gemm_nt_mfma<true><<<dim3(QKV_N / 128, (BATCH * SEQ) / 128), blk, 0, stream>>>(
      xb, wqb, nullptr, nullptr, qkvb, BATCH * SEQ, QKV_N, HID);

  // bf16 MFMA flash attention (software-pipelined) -> attb (bf16)
  attn_mfma<<<dim3(BATCH * NH, SEQ / 64), blk, 0, stream>>>(qkvb, attb);

  // out projection: out = attb @ wob^T + b_out  (f32 out)
  gemm_nt_mfma<false><<<dim3(HID / 128, (BATCH * SEQ) / 128), blk, 0, stream>>>(
      attb, wob, b_out, out, nullptr, BATCH * SEQ, HID, HID);
}

// Round 8
// 132.529 us; speedup vs baseline: 1.3314x; 1.0256x over previous
//
#include <hip/hip_runtime.h>
#include <hip/hip_bf16.h>
#include <cstdint>
#include <cstddef>

#define SEQ    2048
#define BATCH  2
#define HID    768
#define NH     12
#define HD     64
#define QKV_N  2304

typedef __attribute__((ext_vector_type(8))) short bf16x8;
typedef __attribute__((ext_vector_type(4))) float f32x4;

static __device__ __forceinline__ short f2bf(float x) {
  __hip_bfloat16 h = __float2bfloat16(x);  // RNE
  short s;
  __builtin_memcpy(&s, &h, 2);
  return s;
}
static __device__ __forceinline__ float bf2f(short s) {
  __hip_bfloat16 h;
  __builtin_memcpy(&h, &s, 2);
  return __bfloat162float(h);
}

// ---------------------------------------------------------------------------
// Fused f32 -> bf16 conversion for the three inputs (one launch).
// ---------------------------------------------------------------------------
__global__ __launch_bounds__(256)
void cvt3_f32_bf16(const float* __restrict__ s0, short* __restrict__ d0,
                   const float* __restrict__ s1, short* __restrict__ d1,
                   const float* __restrict__ s2, short* __restrict__ d2) {
  int bid = blockIdx.x;
  const float* src;
  short* dst;
  if (bid < 1536)      { src = s0; dst = d0; }
  else if (bid < 2400) { src = s1; dst = d1; bid -= 1536; }
  else                 { src = s2; dst = d2; bid -= 2400; }
  const int i = (bid * 256 + threadIdx.x) * 8;
  const float4 a = *reinterpret_cast<const float4*>(src + i);
  const float4 b = *reinterpret_cast<const float4*>(src + i + 4);
  bf16x8 o;
  o[0] = f2bf(a.x); o[1] = f2bf(a.y); o[2] = f2bf(a.z); o[3] = f2bf(a.w);
  o[4] = f2bf(b.x); o[5] = f2bf(b.y); o[6] = f2bf(b.z); o[7] = f2bf(b.w);
  *reinterpret_cast<bf16x8*>(dst + i) = o;
}

// ---------------------------------------------------------------------------
// bf16 MFMA GEMM NT (m97 structure, known-good).
// ---------------------------------------------------------------------------
template <bool BF16_OUT>
__global__ __launch_bounds__(256)
void gemm_nt_mfma(const short* __restrict__ A, const short* __restrict__ B,
                  const float* __restrict__ bias,
                  float* __restrict__ Cf, short* __restrict__ Cb,
                  int M, int N, int K) {
  __shared__ short As[128][64];   // 16 KB
  __shared__ short Bs[128][64];   // 16 KB

  const int t = threadIdx.x;
  const int w = t >> 6;
  const int l = t & 63;
  const int g = l >> 4;
  const int n = l & 15;

  const int m0 = blockIdx.y * 128;
  const int n0 = blockIdx.x * 128;
  const int wr = (w >> 1) * 64;
  const int wc = (w & 1) * 64;

  const int srow = w * 32 + (l >> 3);
  const int scol = (l & 7) * 8;
  const short* Ag = A + (size_t)(m0 + srow) * K + scol;
  const short* Bg = B + (size_t)(n0 + srow) * K + scol;

  f32x4 acc[4][4] = {};

  for (int k0 = 0; k0 < K; k0 += 64) {
    __syncthreads();
#pragma unroll
    for (int it = 0; it < 4; ++it) {
      __builtin_amdgcn_global_load_lds(
          (const __attribute__((address_space(1))) void*)(Ag + (size_t)(it * 8) * K + k0),
          (__attribute__((address_space(3))) void*)(&As[w * 32 + it * 8][0]),
          16, 0, 0);
    }
#pragma unroll
    for (int it = 0; it < 4; ++it) {
      __builtin_amdgcn_global_load_lds(
          (const __attribute__((address_space(1))) void*)(Bg + (size_t)(it * 8) * K + k0),
          (__attribute__((address_space(3))) void*)(&Bs[w * 32 + it * 8][0]),
          16, 0, 0);
    }
    __syncthreads();

#pragma unroll
    for (int kk = 0; kk < 2; ++kk) {
      bf16x8 af[4], bfr[4];
#pragma unroll
      for (int m = 0; m < 4; ++m)
        af[m] = *reinterpret_cast<const bf16x8*>(&As[wr + m * 16 + n][kk * 32 + g * 8]);
#pragma unroll
      for (int j = 0; j < 4; ++j)
        bfr[j] = *reinterpret_cast<const bf16x8*>(&Bs[wc + j * 16 + n][kk * 32 + g * 8]);
#pragma unroll
      for (int m = 0; m < 4; ++m)
#pragma unroll
        for (int j = 0; j < 4; ++j)
          acc[m][j] = __builtin_amdgcn_mfma_f32_16x16x32_bf16(af[m], bfr[j], acc[m][j], 0, 0, 0);
    }
  }

#pragma unroll
  for (int m = 0; m < 4; ++m) {
#pragma unroll
    for (int r = 0; r < 4; ++r) {
      const size_t row = m0 + wr + m * 16 + g * 4 + r;
#pragma unroll
      for (int j = 0; j < 4; ++j) {
        const int col = n0 + wc + j * 16 + n;
        float v = acc[m][j][r];
        if (bias) v += bias[col];
        if (BF16_OUT) Cb[row * N + col] = f2bf(v);
        else          Cf[row * N + col] = v;
      }
    }
  }
}

// ---------------------------------------------------------------------------
// Flash attention, bf16 MFMA, swapped operands, 8 waves / 512 threads.
// KVBLK = 128 per iteration; wave w: qq = w&3 owns q-rows [q0+qq*16, +16),
// kh = w>>2 processes kv-half [kh*64, kh*64+64) of each staged tile.
// -> 24 waves/CU (vs 12) at identical HBM traffic, balanced grid (768 blocks
//    = exactly 3 blocks/CU).
// Phase schedule (2 barriers / 128 kv):
//   phase1: write V(j) regs->Vt | QK^T(j) from Kx | issue K(j+1) loads
//   phase2: write K(j+1)->Kx | softmax(j) | PV(j) from Vt | issue V(j+1)
// End: exact flash merge of the two kv-half partials (o, m, l) via LDS.
// LDS: Kx[128][72] 18.4K + Vt[64][136] 17.4K + Ps[8][16][64] 16K = 52.2 KB.
//   Vt stride 136 (sb=68, 17 odd-ish): row index enters bank group -> V
//   b128 reads conflict-free with only the coarse (d>>4)<<4 column XOR.
//   Ps stride 64 + fine XOR (n&7)<<3 on columns (write short4 / read b128
//   use the same involution; granules 4 and 8 both respect XOR bits 3-5).
// ---------------------------------------------------------------------------
__global__ __launch_bounds__(512)
void attn_mfma(const short* __restrict__ qkv, short* __restrict__ att) {
  const int bh = blockIdx.x;           // 0..23
  const int qt = blockIdx.y;           // 0..31
  const int b  = bh / NH;
  const int h0 = bh % NH;
  const int q0 = qt * 64;

  const int t  = threadIdx.x;
  const int w  = t >> 6;               // wave 0..7
  const int l  = t & 63;
  const int g  = l >> 4;               // k-slot group 0..3
  const int n  = l & 15;               // q column owned by this lane
  const int qq = w & 3;                // q-quarter
  const int kh = w >> 2;               // kv half

  __shared__ short Kx[128][72];        // 18,432 B
  __shared__ short Vt[64][136];        // 17,408 B
  __shared__ short Ps[8][16][64];      // 16,384 B   (total 52,224)

  const short* baseq = qkv + (size_t)b * SEQ * QKV_N + h0 * HD;
  const short* Kg    = baseq + HID;
  const short* Vg    = baseq + 2 * HID;

  // ---- Q B-fragments, pre-scaled by 0.125 (exact in bf16) ----
  bf16x8 qf[2];
  {
    const short* qrow = baseq + (size_t)(q0 + qq * 16 + n) * QKV_N;
#pragma unroll
    for (int c = 0; c < 2; ++c) {
      bf16x8 raw = *reinterpret_cast<const bf16x8*>(qrow + c * 32 + g * 8);
#pragma unroll
      for (int j = 0; j < 8; ++j) qf[c][j] = f2bf(bf2f(raw[j]) * 0.125f);
    }
  }

  f32x4 o[4] = {{0.f,0.f,0.f,0.f},{0.f,0.f,0.f,0.f},
                {0.f,0.f,0.f,0.f},{0.f,0.f,0.f,0.f}};
  float mrow = -3e38f;
  float lrow = 0.f;

  const int sr   = t >> 2;             // staging row 0..127
  const int sb   = t & 3;              // staging 16-col block
  const int vcol = sr ^ (sb << 4);     // Vt column for this thread's V rows
  const int pswz = (n & 7) << 3;       // Ps fine column XOR

  // ---- prologue: K(0) -> Kx, V(0) -> regs ----
  bf16x8 kA, kB, vA, vB;
  {
    const short* kp = Kg + (size_t)sr * QKV_N + sb * 16;
    kA = *reinterpret_cast<const bf16x8*>(kp);
    kB = *reinterpret_cast<const bf16x8*>(kp + 8);
    *reinterpret_cast<bf16x8*>(&Kx[sr][sb * 16])     = kA;
    *reinterpret_cast<bf16x8*>(&Kx[sr][sb * 16 + 8]) = kB;
    const short* vp = Vg + (size_t)sr * QKV_N + sb * 16;
    vA = *reinterpret_cast<const bf16x8*>(vp);
    vB = *reinterpret_cast<const bf16x8*>(vp + 8);
  }
  __syncthreads();

  for (int j = 0; j < SEQ / 128; ++j) {
    const bool have_next = (j + 1) < SEQ / 128;

    // ---- phase1: write V(j) -> Vt (transposed, coarse XOR) ----
#pragma unroll
    for (int jj = 0; jj < 8; ++jj) Vt[sb * 16 + jj][vcol]     = vA[jj];
#pragma unroll
    for (int jj = 0; jj < 8; ++jj) Vt[sb * 16 + 8 + jj][vcol] = vB[jj];

    // ---- QK^T(j) on this wave's kv half ----
    f32x4 sc[4] = {{0.f,0.f,0.f,0.f},{0.f,0.f,0.f,0.f},
                   {0.f,0.f,0.f,0.f},{0.f,0.f,0.f,0.f}};
#pragma unroll
    for (int c = 0; c < 2; ++c)
#pragma unroll
      for (int kt = 0; kt < 4; ++kt) {
        bf16x8 kb = *reinterpret_cast<const bf16x8*>(
            &Kx[kh * 64 + kt * 16 + n][c * 32 + g * 8]);
        sc[kt] = __builtin_amdgcn_mfma_f32_16x16x32_bf16(kb, qf[c], sc[kt], 0, 0, 0);
      }

    // ---- issue K(j+1) global loads (written next phase) ----
    if (have_next) {
      const short* kp = Kg + (size_t)((j + 1) * 128 + sr) * QKV_N + sb * 16;
      kA = *reinterpret_cast<const bf16x8*>(kp);
      kB = *reinterpret_cast<const bf16x8*>(kp + 8);
    }
    __syncthreads();   // Vt ready for PV; Kx free for overwrite

    // ---- phase2: write K(j+1) -> Kx ----
    if (have_next) {
      *reinterpret_cast<bf16x8*>(&Kx[sr][sb * 16])     = kA;
      *reinterpret_cast<bf16x8*>(&Kx[sr][sb * 16 + 8]) = kB;
    }

    // ---- softmax(j), defer-max (THR = 8) ----
    {
      float pm = fmaxf(fmaxf(sc[0][0], sc[0][1]), fmaxf(sc[0][2], sc[0][3]));
#pragma unroll
      for (int kt = 1; kt < 4; ++kt)
        pm = fmaxf(pm, fmaxf(fmaxf(sc[kt][0], sc[kt][1]),
                             fmaxf(sc[kt][2], sc[kt][3])));
      pm = fmaxf(pm, __shfl_xor(pm, 16));
      pm = fmaxf(pm, __shfl_xor(pm, 32));
      if (__any(pm - mrow > 8.f)) {       // wave-uniform branch
        const float mnew = fmaxf(mrow, pm);
        const float corr = __expf(mrow - mnew);
        mrow = mnew;
        lrow *= corr;
#pragma unroll
        for (int dt = 0; dt < 4; ++dt)
#pragma unroll
          for (int r = 0; r < 4; ++r) o[dt][r] *= corr;
      }
      float psum = 0.f;
#pragma unroll
      for (int kt = 0; kt < 4; ++kt) {
        short4 pk;
        float p0 = __expf(sc[kt][0] - mrow);
        float p1 = __expf(sc[kt][1] - mrow);
        float p2 = __expf(sc[kt][2] - mrow);
        float p3 = __expf(sc[kt][3] - mrow);
        psum += (p0 + p1) + (p2 + p3);
        pk.x = f2bf(p0); pk.y = f2bf(p1); pk.z = f2bf(p2); pk.w = f2bf(p3);
        *reinterpret_cast<short4*>(&Ps[w][n][(kt * 16 + g * 4) ^ pswz]) = pk;
      }
      lrow += psum;
    }
    // Ps is wave-local: ds_write -> ds_read ordering via lgkmcnt.

    // ---- PV(j): o[dt][r] = O[q=n][d = dt*16 + g*4 + r] (this kv half) ----
#pragma unroll
    for (int c = 0; c < 2; ++c) {
      bf16x8 pb = *reinterpret_cast<const bf16x8*>(
          &Ps[w][n][(c * 32 + g * 8) ^ pswz]);
#pragma unroll
      for (int dt = 0; dt < 4; ++dt) {
        bf16x8 va = *reinterpret_cast<const bf16x8*>(
            &Vt[dt * 16 + n][(kh * 64 + c * 32 + g * 8) ^ (dt << 4)]);
        o[dt] = __builtin_amdgcn_mfma_f32_16x16x32_bf16(va, pb, o[dt], 0, 0, 0);
      }
    }

    // ---- issue V(j+1) global loads (written next phase1) ----
    if (have_next) {
      const short* vp = Vg + (size_t)((j + 1) * 128 + sr) * QKV_N + sb * 16;
      vA = *reinterpret_cast<const bf16x8*>(vp);
      vB = *reinterpret_cast<const bf16x8*>(vp + 8);
    }
    __syncthreads();   // Kx ready for j+1; Vt free for overwrite
  }

  // ---- merge kv-half partials (exact flash merge), reuse Kx as f32 buf ----
  float* mb = (float*)&Kx[0][0];       // 4608 floats = 18,432 B, exact fit
  const int slot = (qq * 64 + l) * 18;
  if (kh == 1) {
#pragma unroll
    for (int dt = 0; dt < 4; ++dt)
#pragma unroll
      for (int r = 0; r < 4; ++r) mb[slot + dt * 4 + r] = o[dt][r];
    mb[slot + 16] = mrow;
    mb[slot + 17] = lrow;
  }
  __syncthreads();
  if (kh == 0) {
    const float m2 = mb[slot + 16];
    const float l2 = mb[slot + 17];
    const float mn = fmaxf(mrow, m2);
    const float ca = __expf(mrow - mn);
    const float cb = __expf(m2 - mn);
    float lm = lrow * ca + l2 * cb;
    lm += __shfl_xor(lm, 16);
    lm += __shfl_xor(lm, 32);
    const float linv = 1.f / lm;
    short* orow = att + (size_t)(b * SEQ + q0 + qq * 16 + n) * HID + h0 * HD;
#pragma unroll
    for (int dt = 0; dt < 4; ++dt) {
      short4 ov;
      ov.x = f2bf((o[dt][0] * ca + mb[slot + dt * 4 + 0] * cb) * linv);
      ov.y = f2bf((o[dt][1] * ca + mb[slot + dt * 4 + 1] * cb) * linv);
      ov.z = f2bf((o[dt][2] * ca + mb[slot + dt * 4 + 2] * cb) * linv);
      ov.w = f2bf((o[dt][3] * ca + mb[slot + dt * 4 + 3] * cb) * linv);
      *reinterpret_cast<short4*>(&orow[dt * 16 + g * 4]) = ov;
    }
  }
}

// ---------------------------------------------------------------------------
extern "C" void kernel_launch(void* const* d_in, const int* in_sizes, int n_in,
                              void* d_out, int out_size, void* d_ws, size_t ws_size,
                              hipStream_t stream) {
  const float* x     = (const float*)d_in[0];  // [2,2048,768]
  const float* w_qkv = (const float*)d_in[1];  // [2304,768]
  const float* w_out = (const float*)d_in[2];  // [768,768]
  const float* b_out = (const float*)d_in[3];  // [768]
  float* out = (float*)d_out;                  // [2,2048,768]

  const int NX  = BATCH * SEQ * HID;   // 3,145,728
  const int NWQ = QKV_N * HID;         // 1,769,472
  const int NWO = HID * HID;           //   589,824

  char* ws = (char*)d_ws;
  short* xb   = (short*)ws;  ws += (size_t)NX  * 2;
  short* wqb  = (short*)ws;  ws += (size_t)NWQ * 2;
  short* wob  = (short*)ws;  ws += (size_t)NWO * 2;
  short* qkvb = (short*)ws;  ws += (size_t)BATCH * SEQ * QKV_N * 2;
  short* attb = (short*)ws;  // [4096,768] bf16

  cvt3_f32_bf16<<<dim3(2688), dim3(256), 0, stream>>>(x, xb, w_qkv, wqb, w_out, wob);

  // QKV projection: [4096,2304] = xb @ wqb^T  (bf16 out)
  gemm_nt_mfma<true><<<dim3(QKV_N / 128, (BATCH * SEQ) / 128), dim3(256), 0, stream>>>(
      xb, wqb, nullptr, nullptr, qkvb, BATCH * SEQ, QKV_N, HID);

  // bf16 MFMA flash attention (8-wave kv-split) -> attb (bf16)
  attn_mfma<<<dim3(BATCH * NH, SEQ / 64), dim3(512), 0, stream>>>(qkvb, attb);

  // out projection: out = attb @ wob^T + b_out  (f32 out)
  gemm_nt_mfma<false><<<dim3(HID / 128, (BATCH * SEQ) / 128), dim3(256), 0, stream>>>(
      attb, wob, b_out, out, nullptr, BATCH * SEQ, HID, HID);
}

// Round 9
// 121.793 us; speedup vs baseline: 1.4488x; 1.0882x over previous
//
#include <hip/hip_runtime.h>
#include <hip/hip_bf16.h>
#include <cstdint>
#include <cstddef>

#define SEQ    2048
#define BATCH  2
#define HID    768
#define NH     12
#define HD     64
#define QKV_N  2304

typedef __attribute__((ext_vector_type(8))) short bf16x8;
typedef __attribute__((ext_vector_type(4))) float f32x4;
typedef __attribute__((ext_vector_type(16))) float f32x16;

static __device__ __forceinline__ short f2bf(float x) {
  __hip_bfloat16 h = __float2bfloat16(x);  // RNE
  short s;
  __builtin_memcpy(&s, &h, 2);
  return s;
}
static __device__ __forceinline__ float bf2f(short s) {
  __hip_bfloat16 h;
  __builtin_memcpy(&h, &s, 2);
  return __bfloat162float(h);
}

// ---------------------------------------------------------------------------
// Fused f32 -> bf16 conversion for the three inputs (one launch).
// ---------------------------------------------------------------------------
__global__ __launch_bounds__(256)
void cvt3_f32_bf16(const float* __restrict__ s0, short* __restrict__ d0,
                   const float* __restrict__ s1, short* __restrict__ d1,
                   const float* __restrict__ s2, short* __restrict__ d2) {
  int bid = blockIdx.x;
  const float* src;
  short* dst;
  if (bid < 1536)      { src = s0; dst = d0; }
  else if (bid < 2400) { src = s1; dst = d1; bid -= 1536; }
  else                 { src = s2; dst = d2; bid -= 2400; }
  const int i = (bid * 256 + threadIdx.x) * 8;
  const float4 a = *reinterpret_cast<const float4*>(src + i);
  const float4 b = *reinterpret_cast<const float4*>(src + i + 4);
  bf16x8 o;
  o[0] = f2bf(a.x); o[1] = f2bf(a.y); o[2] = f2bf(a.z); o[3] = f2bf(a.w);
  o[4] = f2bf(b.x); o[5] = f2bf(b.y); o[6] = f2bf(b.z); o[7] = f2bf(b.w);
  *reinterpret_cast<bf16x8*>(dst + i) = o;
}

// ---------------------------------------------------------------------------
// bf16 MFMA GEMM NT, 128x128 tile (m97 structure, known-good). QKV only.
// ---------------------------------------------------------------------------
template <bool BF16_OUT>
__global__ __launch_bounds__(256)
void gemm_nt_mfma(const short* __restrict__ A, const short* __restrict__ B,
                  const float* __restrict__ bias,
                  float* __restrict__ Cf, short* __restrict__ Cb,
                  int M, int N, int K) {
  __shared__ short As[128][64];
  __shared__ short Bs[128][64];

  const int t = threadIdx.x;
  const int w = t >> 6;
  const int l = t & 63;
  const int g = l >> 4;
  const int n = l & 15;

  const int m0 = blockIdx.y * 128;
  const int n0 = blockIdx.x * 128;
  const int wr = (w >> 1) * 64;
  const int wc = (w & 1) * 64;

  const int srow = w * 32 + (l >> 3);
  const int scol = (l & 7) * 8;
  const short* Ag = A + (size_t)(m0 + srow) * K + scol;
  const short* Bg = B + (size_t)(n0 + srow) * K + scol;

  f32x4 acc[4][4] = {};

  for (int k0 = 0; k0 < K; k0 += 64) {
    __syncthreads();
#pragma unroll
    for (int it = 0; it < 4; ++it) {
      __builtin_amdgcn_global_load_lds(
          (const __attribute__((address_space(1))) void*)(Ag + (size_t)(it * 8) * K + k0),
          (__attribute__((address_space(3))) void*)(&As[w * 32 + it * 8][0]),
          16, 0, 0);
    }
#pragma unroll
    for (int it = 0; it < 4; ++it) {
      __builtin_amdgcn_global_load_lds(
          (const __attribute__((address_space(1))) void*)(Bg + (size_t)(it * 8) * K + k0),
          (__attribute__((address_space(3))) void*)(&Bs[w * 32 + it * 8][0]),
          16, 0, 0);
    }
    __syncthreads();

#pragma unroll
    for (int kk = 0; kk < 2; ++kk) {
      bf16x8 af[4], bfr[4];
#pragma unroll
      for (int m = 0; m < 4; ++m)
        af[m] = *reinterpret_cast<const bf16x8*>(&As[wr + m * 16 + n][kk * 32 + g * 8]);
#pragma unroll
      for (int j = 0; j < 4; ++j)
        bfr[j] = *reinterpret_cast<const bf16x8*>(&Bs[wc + j * 16 + n][kk * 32 + g * 8]);
#pragma unroll
      for (int m = 0; m < 4; ++m)
#pragma unroll
        for (int j = 0; j < 4; ++j)
          acc[m][j] = __builtin_amdgcn_mfma_f32_16x16x32_bf16(af[m], bfr[j], acc[m][j], 0, 0, 0);
    }
  }

#pragma unroll
  for (int m = 0; m < 4; ++m) {
#pragma unroll
    for (int r = 0; r < 4; ++r) {
      const size_t row = m0 + wr + m * 16 + g * 4 + r;
#pragma unroll
      for (int j = 0; j < 4; ++j) {
        const int col = n0 + wc + j * 16 + n;
        float v = acc[m][j][r];
        if (bias) v += bias[col];
        if (BF16_OUT) Cb[row * N + col] = f2bf(v);
        else          Cf[row * N + col] = v;
      }
    }
  }
}

// ---------------------------------------------------------------------------
// bf16 MFMA GEMM NT, 64x64 tile — for out-proj (N=768): grid 12x64 = 768
// blocks = 3/CU (128-tile gave only 192 blocks -> 25% of CUs idle).
// Same 2-barrier + global_load_lds structure.
// ---------------------------------------------------------------------------
__global__ __launch_bounds__(256)
void gemm_nt_mfma64(const short* __restrict__ A, const short* __restrict__ B,
                    const float* __restrict__ bias, float* __restrict__ Cf,
                    int M, int N, int K) {
  __shared__ short As[64][64];   // 8 KB
  __shared__ short Bs[64][64];   // 8 KB

  const int t = threadIdx.x;
  const int w = t >> 6;
  const int l = t & 63;
  const int g = l >> 4;
  const int n = l & 15;

  const int m0 = blockIdx.y * 64;
  const int n0 = blockIdx.x * 64;
  const int wr = (w >> 1) * 32;
  const int wc = (w & 1) * 32;

  const int srow = t >> 3;        // 0..31
  const int scol = (t & 7) * 8;
  const short* Ag = A + (size_t)(m0 + srow) * K + scol;
  const short* Bg = B + (size_t)(n0 + srow) * K + scol;

  f32x4 acc[2][2] = {};

  for (int k0 = 0; k0 < K; k0 += 64) {
    __syncthreads();
#pragma unroll
    for (int it = 0; it < 2; ++it) {
      __builtin_amdgcn_global_load_lds(
          (const __attribute__((address_space(1))) void*)(Ag + (size_t)(it * 32) * K + k0),
          (__attribute__((address_space(3))) void*)(&As[w * 8 + it * 32][0]),
          16, 0, 0);
    }
#pragma unroll
    for (int it = 0; it < 2; ++it) {
      __builtin_amdgcn_global_load_lds(
          (const __attribute__((address_space(1))) void*)(Bg + (size_t)(it * 32) * K + k0),
          (__attribute__((address_space(3))) void*)(&Bs[w * 8 + it * 32][0]),
          16, 0, 0);
    }
    __syncthreads();

#pragma unroll
    for (int kk = 0; kk < 2; ++kk) {
      bf16x8 af[2], bfr[2];
#pragma unroll
      for (int m = 0; m < 2; ++m)
        af[m] = *reinterpret_cast<const bf16x8*>(&As[wr + m * 16 + n][kk * 32 + g * 8]);
#pragma unroll
      for (int j = 0; j < 2; ++j)
        bfr[j] = *reinterpret_cast<const bf16x8*>(&Bs[wc + j * 16 + n][kk * 32 + g * 8]);
#pragma unroll
      for (int m = 0; m < 2; ++m)
#pragma unroll
        for (int j = 0; j < 2; ++j)
          acc[m][j] = __builtin_amdgcn_mfma_f32_16x16x32_bf16(af[m], bfr[j], acc[m][j], 0, 0, 0);
    }
  }

#pragma unroll
  for (int m = 0; m < 2; ++m) {
#pragma unroll
    for (int r = 0; r < 4; ++r) {
      const size_t row = m0 + wr + m * 16 + g * 4 + r;
#pragma unroll
      for (int j = 0; j < 2; ++j) {
        const int col = n0 + wc + j * 16 + n;
        Cf[row * N + col] = acc[m][j][r] + bias[col];
      }
    }
  }
}

// ---------------------------------------------------------------------------
// Flash attention, 32x32x16 MFMA (halves LDS fragment reads per FLOP).
// 8 waves / 512 threads: qq = w>>2 owns q-rows [q0+qq*32, +32),
// kh = w&3 owns kv-quarter [kh*32, +32) of each 128-row staged tile.
// MFMA layouts (m74/m101-verified D; A/B mirror 16x16 convention):
//   A: row = l&31, k = (l>>5)*8 + j     B: col = l&31, k = (l>>5)*8 + j
//   D: col = l&31, row = (reg&3) + 8*(reg>>2) + 4*(l>>5)
// K staged by global_load_lds into LINEAR [128][64] LDS with pre-swizzled
// SOURCE (granule dg = g8 ^ (kv&7)); reads apply the same XOR (T21/m173).
// V reg-staged transposed (swizzled col = y ^ ((d>>4)<<4)); Ps[32][32]/wave
// with granule XOR (q&3). Epilogue: exact 4-way flash merge of kh partials.
// ---------------------------------------------------------------------------
__global__ __launch_bounds__(512)
void attn_mfma(const short* __restrict__ qkv, short* __restrict__ att) {
  const int bh = blockIdx.x;           // 0..23
  const int qt = blockIdx.y;           // 0..31
  const int b  = bh / NH;
  const int h0 = bh % NH;
  const int q0 = qt * 64;

  const int t   = threadIdx.x;
  const int w   = t >> 6;              // wave 0..7
  const int l   = t & 63;
  const int hi  = l >> 5;              // k-half
  const int q31 = l & 31;              // q column owned by this lane
  const int qq  = w >> 2;              // q 32-row group
  const int kh  = w & 3;               // kv quarter

  __shared__ __align__(16) char smem[50176];
  short* KxL = (short*)smem;            // [128][64] linear, 16384 B
  short* VtL = (short*)(smem + 16384);  // [64][136], 17408 B
  short* PsL = (short*)(smem + 33792);  // [8][32][32], 16384 B

  const short* baseq = qkv + (size_t)b * SEQ * QKV_N + h0 * HD;
  const short* Kg    = baseq + HID;
  const short* Vg    = baseq + 2 * HID;

  // ---- Q B-fragments, pre-scaled by 0.125 (exact in bf16) ----
  bf16x8 qf[4];
  {
    const short* qrow = baseq + (size_t)(q0 + qq * 32 + q31) * QKV_N;
#pragma unroll
    for (int c16 = 0; c16 < 4; ++c16) {
      bf16x8 raw = *reinterpret_cast<const bf16x8*>(qrow + c16 * 16 + hi * 8);
#pragma unroll
      for (int j = 0; j < 8; ++j) qf[c16][j] = f2bf(bf2f(raw[j]) * 0.125f);
    }
  }

  f32x16 o0 = {};
  f32x16 o1 = {};
  float mrow = -3e38f;
  float lrow = 0.f;

  const int sr   = t >> 2;             // V staging row (y) 0..127
  const int sb   = t & 3;              // V staging 16-wide d block
  const int vcol = sr ^ (sb << 4);     // swizzled Vt column

  // K-DMA source indices (per thread, 2 instrs)
  const int kv0  = t >> 3;             // instr0 kv row (0..63)
  const int dg0  = (t & 7) ^ (kv0 & 7);
  const int kv1  = kv0 + 64;
  const int dg1  = (t & 7) ^ (kv1 & 7);

  // ---- prologue: DMA K(0), load V(0) into regs ----
  __builtin_amdgcn_global_load_lds(
      (const __attribute__((address_space(1))) void*)(Kg + (size_t)kv0 * QKV_N + dg0 * 8),
      (__attribute__((address_space(3))) void*)(KxL + w * 512), 16, 0, 0);
  __builtin_amdgcn_global_load_lds(
      (const __attribute__((address_space(1))) void*)(Kg + (size_t)kv1 * QKV_N + dg1 * 8),
      (__attribute__((address_space(3))) void*)(KxL + w * 512 + 4096), 16, 0, 0);
  bf16x8 vA, vB;
  {
    const short* vp = Vg + (size_t)sr * QKV_N + sb * 16;
    vA = *reinterpret_cast<const bf16x8*>(vp);
    vB = *reinterpret_cast<const bf16x8*>(vp + 8);
  }
  __syncthreads();   // drains K(0) DMA (compiler vmcnt(0) before barrier)

  const int krow = kh * 32 + q31;      // this lane's K row (global within tile)
  const int kxor = l & 7;              // read-side granule XOR

  for (int j = 0; j < SEQ / 128; ++j) {
    const bool have_next = (j + 1) < SEQ / 128;

    // ---- phase1: write V(j) -> Vt (transposed, swizzled) ----
#pragma unroll
    for (int idx = 0; idx < 8; ++idx) VtL[(sb * 16 + idx) * 136 + vcol]     = vA[idx];
#pragma unroll
    for (int idx = 0; idx < 8; ++idx) VtL[(sb * 16 + 8 + idx) * 136 + vcol] = vB[idx];

    // ---- QK^T(j): sc = S^T[kv = krow][q = q31] over d=64 (4 MFMA) ----
    f32x16 sc = {};
#pragma unroll
    for (int c16 = 0; c16 < 4; ++c16) {
      bf16x8 kb = *reinterpret_cast<const bf16x8*>(
          (const char*)KxL + krow * 128 + (((c16 * 2 + hi) ^ kxor) << 4));
      sc = __builtin_amdgcn_mfma_f32_32x32x16_bf16(kb, qf[c16], sc, 0, 0, 0);
    }
    __syncthreads();   // Vt complete for PV; Kx reads done -> DMA safe

    // ---- phase2: issue K(j+1) DMA + V(j+1) loads early ----
    if (have_next) {
      const size_t rb = (size_t)(j + 1) * 128;
      __builtin_amdgcn_global_load_lds(
          (const __attribute__((address_space(1))) void*)(Kg + (rb + kv0) * QKV_N + dg0 * 8),
          (__attribute__((address_space(3))) void*)(KxL + w * 512), 16, 0, 0);
      __builtin_amdgcn_global_load_lds(
          (const __attribute__((address_space(1))) void*)(Kg + (rb + kv1) * QKV_N + dg1 * 8),
          (__attribute__((address_space(3))) void*)(KxL + w * 512 + 4096), 16, 0, 0);
      const short* vp = Vg + (rb + sr) * QKV_N + sb * 16;
      vA = *reinterpret_cast<const bf16x8*>(vp);
      vB = *reinterpret_cast<const bf16x8*>(vp + 8);
    }

    // ---- softmax(j): lane owns 16 of 32 kv rows for q = q31 ----
    {
      float pm = fmaxf(fmaxf(sc[0], sc[1]), fmaxf(sc[2], sc[3]));
#pragma unroll
      for (int r = 4; r < 16; r += 4)
        pm = fmaxf(pm, fmaxf(fmaxf(sc[r], sc[r + 1]), fmaxf(sc[r + 2], sc[r + 3])));
      pm = fmaxf(pm, __shfl_xor(pm, 32));
      if (__any(pm - mrow > 8.f)) {     // defer-max (THR=8), wave-uniform
        const float mnew = fmaxf(mrow, pm);
        const float corr = __expf(mrow - mnew);
        mrow = mnew;
        lrow *= corr;
#pragma unroll
        for (int r = 0; r < 16; ++r) { o0[r] *= corr; o1[r] *= corr; }
      }
      float psum = 0.f;
#pragma unroll
      for (int rr = 0; rr < 4; ++rr) {
        const float p0 = __expf(sc[rr * 4 + 0] - mrow);
        const float p1 = __expf(sc[rr * 4 + 1] - mrow);
        const float p2 = __expf(sc[rr * 4 + 2] - mrow);
        const float p3 = __expf(sc[rr * 4 + 3] - mrow);
        psum += (p0 + p1) + (p2 + p3);
        short4 pk;
        pk.x = f2bf(p0); pk.y = f2bf(p1); pk.z = f2bf(p2); pk.w = f2bf(p3);
        // P[q=q31][y-local = rr*8 + hi*4 + (0..3)], granule-XOR (q&3)
        *reinterpret_cast<short4*>(
            &PsL[w * 1024 + q31 * 32 + ((rr ^ (q31 & 3)) << 3) + hi * 4]) = pk;
      }
      lrow += psum;
    }
    // Ps wave-local: ds_write -> ds_read ordered by lgkmcnt.

    // ---- PV(j): o^T[d = dt*32+row][q = q31] over this wave's 32 kv ----
#pragma unroll
    for (int c = 0; c < 2; ++c) {
      bf16x8 pb = *reinterpret_cast<const bf16x8*>(
          &PsL[w * 1024 + q31 * 32 + ((((c << 1) + hi) ^ (q31 & 3)) << 3)]);
      {
        const int vrow = q31;           // dt = 0
        bf16x8 va = *reinterpret_cast<const bf16x8*>(
            &VtL[vrow * 136 + ((kh * 32 + c * 16 + hi * 8) ^ ((vrow >> 4) << 4))]);
        o0 = __builtin_amdgcn_mfma_f32_32x32x16_bf16(va, pb, o0, 0, 0, 0);
      }
      {
        const int vrow = 32 + q31;      // dt = 1
        bf16x8 va = *reinterpret_cast<const bf16x8*>(
            &VtL[vrow * 136 + ((kh * 32 + c * 16 + hi * 8) ^ ((vrow >> 4) << 4))]);
        o1 = __builtin_amdgcn_mfma_f32_32x32x16_bf16(va, pb, o1, 0, 0, 0);
      }
    }
    __syncthreads();   // drains K(j+1) DMA + V loads; Vt free for overwrite
  }

  // ---- combine the two k-half l partials (lanes l, l^32 share q) ----
  lrow += __shfl_xor(lrow, 32);

  // ---- exact flash merge of the 4 kh partials (two-step tree) ----
  float* mbf = (float*)smem;           // 34 f32 x 64 lanes x 4 slots = 34,816 B
  const int base = (qq * 2 + (kh >> 1)) * 2176 + l * 34;
  if (kh & 1) {                        // kh = 1,3 write
#pragma unroll
    for (int r = 0; r < 16; ++r) { mbf[base + r] = o0[r]; mbf[base + 16 + r] = o1[r]; }
    mbf[base + 32] = mrow;
    mbf[base + 33] = lrow;
  }
  __syncthreads();
  if (!(kh & 1)) {                     // kh = 0,2 merge partner kh+1
    const float m2 = mbf[base + 32];
    const float l2 = mbf[base + 33];
    const float mn = fmaxf(mrow, m2);
    const float ca = __expf(mrow - mn);
    const float cb = __expf(m2 - mn);
#pragma unroll
    for (int r = 0; r < 16; ++r) {
      o0[r] = o0[r] * ca + mbf[base + r] * cb;
      o1[r] = o1[r] * ca + mbf[base + 16 + r] * cb;
    }
    lrow = lrow * ca + l2 * cb;
    mrow = mn;
  }
  __syncthreads();
  const int base2 = qq * 2176 + l * 34;
  if (kh == 2) {                       // merged (2,3) -> slot qq
#pragma unroll
    for (int r = 0; r < 16; ++r) { mbf[base2 + r] = o0[r]; mbf[base2 + 16 + r] = o1[r]; }
    mbf[base2 + 32] = mrow;
    mbf[base2 + 33] = lrow;
  }
  __syncthreads();
  if (kh == 0) {                       // final merge + normalize + store
    const float m2 = mbf[base2 + 32];
    const float l2 = mbf[base2 + 33];
    const float mn = fmaxf(mrow, m2);
    const float ca = __expf(mrow - mn);
    const float cb = __expf(m2 - mn);
    const float lm = lrow * ca + l2 * cb;
    const float linv = 1.f / lm;
    short* orow = att + (size_t)(b * SEQ + q0 + qq * 32 + q31) * HID + h0 * HD;
#pragma unroll
    for (int rr = 0; rr < 4; ++rr) {
      short4 ov;
      ov.x = f2bf((o0[rr * 4 + 0] * ca + mbf[base2 + rr * 4 + 0] * cb) * linv);
      ov.y = f2bf((o0[rr * 4 + 1] * ca + mbf[base2 + rr * 4 + 1] * cb) * linv);
      ov.z = f2bf((o0[rr * 4 + 2] * ca + mbf[base2 + rr * 4 + 2] * cb) * linv);
      ov.w = f2bf((o0[rr * 4 + 3] * ca + mbf[base2 + rr * 4 + 3] * cb) * linv);
      *reinterpret_cast<short4*>(&orow[rr * 8 + hi * 4]) = ov;
      short4 ow;
      ow.x = f2bf((o1[rr * 4 + 0] * ca + mbf[base2 + 16 + rr * 4 + 0] * cb) * linv);
      ow.y = f2bf((o1[rr * 4 + 1] * ca + mbf[base2 + 16 + rr * 4 + 1] * cb) * linv);
      ow.z = f2bf((o1[rr * 4 + 2] * ca + mbf[base2 + 16 + rr * 4 + 2] * cb) * linv);
      ow.w = f2bf((o1[rr * 4 + 3] * ca + mbf[base2 + 16 + rr * 4 + 3] * cb) * linv);
      *reinterpret_cast<short4*>(&orow[32 + rr * 8 + hi * 4]) = ow;
    }
  }
}

// ---------------------------------------------------------------------------
extern "C" void kernel_launch(void* const* d_in, const int* in_sizes, int n_in,
                              void* d_out, int out_size, void* d_ws, size_t ws_size,
                              hipStream_t stream) {
  const float* x     = (const float*)d_in[0];  // [2,2048,768]
  const float* w_qkv = (const float*)d_in[1];  // [2304,768]
  const float* w_out = (const float*)d_in[2];  // [768,768]
  const float* b_out = (const float*)d_in[3];  // [768]
  float* out = (float*)d_out;                  // [2,2048,768]

  const int NX  = BATCH * SEQ * HID;   // 3,145,728
  const int NWQ = QKV_N * HID;         // 1,769,472
  const int NWO = HID * HID;           //   589,824

  char* ws = (char*)d_ws;
  short* xb   = (short*)ws;  ws += (size_t)NX  * 2;
  short* wqb  = (short*)ws;  ws += (size_t)NWQ * 2;
  short* wob  = (short*)ws;  ws += (size_t)NWO * 2;
  short* qkvb = (short*)ws;  ws += (size_t)BATCH * SEQ * QKV_N * 2;
  short* attb = (short*)ws;  // [4096,768] bf16

  cvt3_f32_bf16<<<dim3(2688), dim3(256), 0, stream>>>(x, xb, w_qkv, wqb, w_out, wob);

  // QKV projection: [4096,2304] = xb @ wqb^T  (bf16 out)
  gemm_nt_mfma<true><<<dim3(QKV_N / 128, (BATCH * SEQ) / 128), dim3(256), 0, stream>>>(
      xb, wqb, nullptr, nullptr, qkvb, BATCH * SEQ, QKV_N, HID);

  // bf16 MFMA flash attention (32x32, DMA-K) -> attb (bf16)
  attn_mfma<<<dim3(BATCH * NH, SEQ / 64), dim3(512), 0, stream>>>(qkvb, attb);

  // out projection (64x64 tiles -> 768 blocks = 3/CU): out = attb @ wob^T + b_out
  gemm_nt_mfma64<<<dim3(HID / 64, (BATCH * SEQ) / 64), dim3(256), 0, stream>>>(
      attb, wob, b_out, out, BATCH * SEQ, HID, HID);
}